// Round 6
// baseline (723.077 us; speedup 1.0000x reference)
//
#include <hip/hip_runtime.h>
#include <math.h>

#define NCH 8
#define HID 20

// ---- workspace layout (float offsets) ----
#define OFF_F    0u            // 13*576*81   = 606528
#define OFF_BAB  606528u       // 13*576*9    = 67392
#define OFF_E    673920u       // 13*9*576*28 = 1886976  (row: E[0..24], [25]=beta)
#define OFF_I1   2560896u      // 8*64*64
#define OFF_I2   2593664u      // 8*32*32
#define OFF_XA   2601856u      // 8*8*128*128
#define OFF_XB   3650432u
#define OFF_X1A  4699008u      // 8*8*64*64
#define OFF_X1B  4961152u
#define OFF_X2A  5223296u      // 8*8*32*32
#define OFF_X2B  5288832u
#define OFF_EPAD 5354368u      // 13 * 5184 * 32 = 2156544  (interior class, 128B rows)
// total 7510912 floats ~= 30.0 MB

#define EBLKF ((size_t)9 * 576 * 28)
#define EMIDF ((size_t)4 * 576 * 28)
#define EPBLK ((size_t)5184 * 32)

// K1: precomp_f (F/Bab) + img_down fused (independent work, block-split).
__global__ __launch_bounds__(256) void precomp_f_imgdown(
    const float* __restrict__ iW1, const float* __restrict__ iW2, const float* __restrict__ ib1,
    const float* __restrict__ bW1, const float* __restrict__ bW2, const float* __restrict__ bb1,
    float* __restrict__ F, float* __restrict__ Bab,
    const float* __restrict__ image, float* __restrict__ i1, float* __restrict__ i2)
{
  if (blockIdx.x >= 2370) {
    int tid = (blockIdx.x - 2370) * 256 + threadIdx.x;
    if (tid < 8 * 64 * 64) {
      int xx = tid % 64, y = (tid / 64) % 64, b = tid / 4096;
      const float* p = image + ((size_t)b * 128 + y * 2) * 128 + xx * 2;
      i1[tid] = 0.25f * (p[0] + p[1] + p[128] + p[129]);
    } else {
      int t = tid - 8 * 64 * 64;
      if (t >= 8 * 32 * 32) return;
      int xx = t % 32, y = (t / 32) % 32, b = t / 1024;
      const float* p = image + ((size_t)b * 128 + y * 4) * 128 + xx * 4;
      float s = 0.f;
      #pragma unroll
      for (int rr = 0; rr < 4; ++rr)
        #pragma unroll
        for (int cc = 0; cc < 4; ++cc) s += p[rr * 128 + cc];
      i2[t] = s * 0.0625f;
    }
    return;
  }
  int tid = blockIdx.x * 256 + threadIdx.x;
  if (tid >= 13 * 576 * 81) return;
  int ab9 = tid % 81;
  int rest = tid / 81;
  int p = rest % 576;
  int blk = rest / 576;
  if (blk == 0 && p >= 72) return;
  int ab = ab9 / 9, apbp = ab9 % 9;
  const float *W2, *W1, *b1;
  if (blk == 0) { W2 = iW2; W1 = iW1; b1 = ib1; }
  else {
    W2 = bW2 + (size_t)(blk - 1) * 576 * HID * 9;
    W1 = bW1 + (size_t)(blk - 1) * 64 * HID * 9;
    b1 = bb1 + (size_t)(blk - 1) * 64 * HID;
  }
  int g = p / 9;
  const float* w2p = W2 + (size_t)p * HID * 9 + ab;
  const float* w1p = W1 + (size_t)g * HID * 9 + apbp;
  float s = 0.f;
  #pragma unroll
  for (int cc = 0; cc < HID; ++cc) s = fmaf(w2p[cc * 9], w1p[cc * 9], s);
  F[(size_t)(blk * 576 + p) * 81 + ab9] = s;
  if (apbp == 0) {
    const float* b1p = b1 + g * HID;
    float sb = 0.f;
    #pragma unroll
    for (int cc = 0; cc < HID; ++cc) sb = fmaf(w2p[cc * 9], b1p[cc], sb);
    Bab[(size_t)(blk * 576 + p) * 9 + ab] = sb;
  }
}

// K2: E-class tables + padded interior copy (Epad rows = 32 floats, 128B aligned).
__global__ __launch_bounds__(256) void precomp_e(
    const float* __restrict__ F, const float* __restrict__ Bab,
    const float* __restrict__ ib2, const float* __restrict__ bb2,
    float* __restrict__ E, float* __restrict__ Epad)
{
  int tid = blockIdx.x * 256 + threadIdx.x;
  if (tid >= 13 * 9 * 576 * 25) return;
  int uv = tid % 25;
  int rest = tid / 25;
  int p = rest % 576;
  int rest2 = rest / 576;
  int cls = rest2 % 9;
  int blk = rest2 / 9;
  if (blk == 0 && p >= 72) return;
  int yc = cls / 3, xc = cls % 3;
  int alo = (yc == 0) ? 1 : 0, ahi = (yc == 2) ? 1 : 2;
  int blo = (xc == 0) ? 1 : 0, bhi = (xc == 2) ? 1 : 2;
  int u = uv / 5, v = uv % 5;
  const float* Fp = F + (size_t)(blk * 576 + p) * 81;
  float s = 0.f;
  for (int a = alo; a <= ahi; ++a) {
    int a2 = u - a;
    if (a2 < 0 || a2 > 2) continue;
    for (int bq = blo; bq <= bhi; ++bq) {
      int b2i = v - bq;
      if (b2i < 0 || b2i > 2) continue;
      s += Fp[(a * 3 + bq) * 9 + a2 * 3 + b2i];
    }
  }
  float* Ep = E + (size_t)((blk * 9 + cls) * 576 + p) * 28;
  Ep[uv] = s;
  float beta = 0.f;
  if (uv == 0) {
    beta = (blk == 0) ? ib2[p] : bb2[(size_t)(blk - 1) * 576 + p];
    const float* Bp = Bab + (size_t)(blk * 576 + p) * 9;
    for (int a = alo; a <= ahi; ++a)
      for (int bq = blo; bq <= bhi; ++bq)
        beta += Bp[a * 3 + bq];
    Ep[25] = beta;
  }
  if (cls == 4) {
    // interior: Epad[blk][p][32]  (p enumerates (o*nci+i)*9+k9 rows already)
    float* q = Epad + blk * EPBLK + (size_t)p * 9 * 32;
    // p here is the (o,i) index; row index within Epad includes k9 via ab?  NO:
    // E rows are per (p, cls) with uv in 0..24; k9 is NOT part of this kernel's
    // indexing (K[...] has 9 taps p-major: p = (o*nci+i)*9 + ab? ) -- p in this
    // kernel is the W2 output channel = (o*nci + i)*9 + ab collapsed as 576 = 64*9.
    // So p already includes the tap: rows map 1:1.
    q = Epad + blk * EPBLK + (size_t)p * 32;
    q[uv] = s;
    if (uv == 0) q[25] = beta;
  }
}

__global__ __launch_bounds__(256) void x_down(
    const float* __restrict__ x, float* __restrict__ x1, float* __restrict__ x2)
{
  int tid = blockIdx.x * 256 + threadIdx.x;
  if (tid < 8 * NCH * 64 * 64) {
    int xx = tid % 64, y = (tid / 64) % 64, rest = tid / 4096;
    const float* p = x + ((size_t)rest * 128 + y * 2) * 128 + xx * 2;
    x1[tid] = 0.25f * (p[0] + p[1] + p[128] + p[129]);
  } else {
    int t = tid - 8 * NCH * 64 * 64;
    if (t >= 8 * NCH * 32 * 32) return;
    int xx = t % 32, y = (t / 32) % 32, rest = t / 1024;
    const float* p = x + ((size_t)rest * 128 + y * 4) * 128 + xx * 4;
    float s = 0.f;
    #pragma unroll
    for (int rr = 0; rr < 4; ++rr)
      #pragma unroll
      for (int cc = 0; cc < 4; ++cc) s += p[rr * 128 + cc];
    x2[t] = s * 0.0625f;
  }
}

#define TW 32
#define TH 32

// Unified per-step kernel. Interior: 32x32 tile, thread = 4-row strip x 2 o-chans.
// E (interior) via Epad 128B rows -> wave-uniform s_load stream; no LDS for E.
__global__ __launch_bounds__(256, 2) void sm_step(
    const float* __restrict__ xi0, float* __restrict__ xo0, const float* __restrict__ im0, const float* __restrict__ Ei0, const float* __restrict__ Ee0, int N0, int nci0,
    const float* __restrict__ xi1, float* __restrict__ xo1, const float* __restrict__ im1, const float* __restrict__ Ei1, const float* __restrict__ Ee1, int N1, int nci1,
    const float* __restrict__ xi2, float* __restrict__ xo2, const float* __restrict__ im2, const float* __restrict__ Ei2, const float* __restrict__ Ee2, int N2, int nci2,
    int i0, int i01, int i012, int e0e, int e01e, int e012e)
{
  __shared__ float xs[NCH][TH + 2][TW + 2];
  __shared__ float is[TH + 4][TW + 4];

  int bid = blockIdx.x;
  const float* __restrict__ xin;
  float* __restrict__ xout;
  const float* __restrict__ img;
  int N, nci;

  if (bid < i012) {
    // ---------------- interior ----------------
    const float* __restrict__ Ei;
    int lb, s;
    if (bid < i0)       { s = 0; lb = bid; }
    else if (bid < i01) { s = 1; lb = bid - i0; }
    else                { s = 2; lb = bid - i01; }
    if (s == 0)      { xin = xi0; xout = xo0; img = im0; Ei = Ei0; N = N0; nci = nci0; }
    else if (s == 1) { xin = xi1; xout = xo1; img = im1; Ei = Ei1; N = N1; nci = nci1; }
    else             { xin = xi2; xout = xo2; img = im2; Ei = Ei2; N = N2; nci = nci2; }

    int og = lb & 3;
    int rem = lb >> 2;
    int tilesx = N / TW;
    int tiles = tilesx * (N / TH);  // N=32 -> 1 tile
    int b = rem / tiles;
    int trem = rem % tiles;
    int ty = trem / tilesx, tx = trem % tilesx;
    int X0 = tx * TW, Y0 = ty * TH;
    const int o0 = og * 2;

    const float* imgb = img + (size_t)b * N * N;
    for (int idx = threadIdx.x; idx < (TH + 4) * (TW + 4); idx += 256) {
      int rr = idx / (TW + 4), cc = idx % (TW + 4);
      int gy = Y0 + rr - 2, gx = X0 + cc - 2;
      float v = 0.f;
      if (gy >= 0 && gy < N && gx >= 0 && gx < N) v = imgb[gy * N + gx];
      is[rr][cc] = v;
    }
    const float* xinb = xin + (size_t)b * nci * N * N;
    for (int idx = threadIdx.x; idx < nci * (TH + 2) * (TW + 2); idx += 256) {
      int cc = idx % (TW + 2);
      int rr = idx / (TW + 2);
      int r2 = rr % (TH + 2);
      int i = rr / (TH + 2);
      int gy = Y0 + r2 - 1, gx = X0 + cc - 1;
      float v = 0.f;
      if (gy >= 0 && gy < N && gx >= 0 && gx < N) v = xinb[(size_t)i * N * N + gy * N + gx];
      xs[i][r2][cc] = v;
    }
    __syncthreads();

    int c = threadIdx.x & 31;
    int r = threadIdx.x >> 5;   // 0..7
    int R = r * 4;              // pixel rows R..R+3; patch rows R..R+7

    float pr[8][5];
    #pragma unroll
    for (int u = 0; u < 8; ++u)
      #pragma unroll
      for (int v = 0; v < 5; ++v) pr[u][v] = is[R + u][c + v];
    asm volatile("" : "+v"(pr[0][0]), "+v"(pr[0][1]), "+v"(pr[0][2]), "+v"(pr[0][3]), "+v"(pr[0][4]),
                     "+v"(pr[1][0]), "+v"(pr[1][1]), "+v"(pr[1][2]), "+v"(pr[1][3]), "+v"(pr[1][4]),
                     "+v"(pr[2][0]), "+v"(pr[2][1]), "+v"(pr[2][2]), "+v"(pr[2][3]), "+v"(pr[2][4]),
                     "+v"(pr[3][0]), "+v"(pr[3][1]), "+v"(pr[3][2]), "+v"(pr[3][3]), "+v"(pr[3][4]));
    asm volatile("" : "+v"(pr[4][0]), "+v"(pr[4][1]), "+v"(pr[4][2]), "+v"(pr[4][3]), "+v"(pr[4][4]),
                     "+v"(pr[5][0]), "+v"(pr[5][1]), "+v"(pr[5][2]), "+v"(pr[5][3]), "+v"(pr[5][4]),
                     "+v"(pr[6][0]), "+v"(pr[6][1]), "+v"(pr[6][2]), "+v"(pr[6][3]), "+v"(pr[6][4]),
                     "+v"(pr[7][0]), "+v"(pr[7][1]), "+v"(pr[7][2]), "+v"(pr[7][3]), "+v"(pr[7][4]));

    float acc[2][4];
    #pragma unroll
    for (int o = 0; o < 2; ++o)
      #pragma unroll
      for (int j = 0; j < 4; ++j) acc[o][j] = 0.f;

    const float* __restrict__ Ea = Ei + (size_t)(o0 * nci) * 9 * 32;
    const float* __restrict__ Eb = Ea + (size_t)nci * 9 * 32;

    #pragma unroll 1
    for (int i = 0; i < nci; ++i) {
      #pragma unroll
      for (int k9 = 0; k9 < 9; ++k9) {
        const int dy = k9 / 3, dx = k9 % 3;
        float xp[4];
        #pragma unroll
        for (int j = 0; j < 4; ++j) xp[j] = xs[i][R + j + dy][c + dx];
        const float* __restrict__ e0 = Ea + (size_t)(i * 9 + k9) * 32;
        const float* __restrict__ e1 = Eb + (size_t)(i * 9 + k9) * 32;
        float k0[4], k1[4];
        #pragma unroll
        for (int j = 0; j < 4; ++j) { k0[j] = e0[25]; k1[j] = e1[25]; }
        #pragma unroll
        for (int u = 0; u < 5; ++u)
          #pragma unroll
          for (int v = 0; v < 5; ++v) {
            const int uv = u * 5 + v;
            const float c0 = e0[uv], c1 = e1[uv];
            #pragma unroll
            for (int j = 0; j < 4; ++j) {
              k0[j] = fmaf(c0, pr[u + j][v], k0[j]);
              k1[j] = fmaf(c1, pr[u + j][v], k1[j]);
            }
          }
        #pragma unroll
        for (int j = 0; j < 4; ++j) {
          acc[0][j] = fmaf(k0[j], xp[j], acc[0][j]);
          acc[1][j] = fmaf(k1[j], xp[j], acc[1][j]);
        }
      }
    }

    const int gx = X0 + c;
    float* yb = xout + (size_t)b * NCH * N * N;
    bool cok = (gx > 0) & (gx < N - 1);
    #pragma unroll
    for (int j = 0; j < 4; ++j) {
      int gy = Y0 + R + j;
      if (cok & (gy > 0) & (gy < N - 1)) {
        float v0 = acc[0][j]; v0 = v0 > 0.f ? v0 : expm1f(v0);
        float v1 = acc[1][j]; v1 = v1 > 0.f ? v1 : expm1f(v1);
        yb[(size_t)o0 * N * N + gy * N + gx] = v0;
        yb[(size_t)(o0 + 1) * N * N + gy * N + gx] = v1;
      }
    }
    return;
  }

  if (bid < e012e) {
    // ---------------- edges (excl corners) ----------------
    const float* __restrict__ E;
    int eb = bid - i012;
    int lb, s;
    if (eb < e0e - i012)        { s = 0; lb = eb; }
    else if (eb < e01e - i012)  { s = 1; lb = eb - (e0e - i012); }
    else                        { s = 2; lb = eb - (e01e - i012); }
    if (s == 0)      { xin = xi0; xout = xo0; img = im0; E = Ee0; N = N0; nci = nci0; }
    else if (s == 1) { xin = xi1; xout = xo1; img = im1; E = Ee1; N = N1; nci = nci1; }
    else             { xin = xi2; xout = xo2; img = im2; E = Ee2; N = N2; nci = nci2; }

    int H = (N - 2 + 63) / 64;
    int half = lb % H;
    int b = (lb / H) % 8;
    int side = lb / (H * 8);

    int lane = threadIdx.x & 63;
    int orow = threadIdx.x >> 6;   // 0..3 (wave-uniform)
    int pos = 1 + half * 64 + lane;
    bool act = pos < N - 1;
    if (!act) pos = 1;

    int y, x, cls;
    if (side == 0)      { y = 0;     x = pos;  cls = 1; }
    else if (side == 1) { y = N - 1; x = pos;  cls = 7; }
    else if (side == 2) { x = 0;     y = pos;  cls = 3; }
    else                { x = N - 1; y = pos;  cls = 5; }

    const float* __restrict__ Ec = E + (size_t)cls * 576 * 28;
    const float* imb = img + (size_t)b * N * N;
    float P[25];
    #pragma unroll
    for (int u = 0; u < 5; ++u)
      #pragma unroll
      for (int v = 0; v < 5; ++v) {
        int gy = y + u - 2, gx = x + v - 2;
        P[u * 5 + v] = (gy >= 0 && gy < N && gx >= 0 && gx < N) ? imb[gy * N + gx] : 0.f;
      }

    const float* xb = xin + (size_t)b * nci * N * N;
    float acc0 = 0.f, acc1 = 0.f;
    const int oA = orow, oB = orow + 4;
    for (int i = 0; i < nci; ++i) {
      #pragma unroll 1
      for (int k9 = 0; k9 < 9; ++k9) {
        int yy = y + k9 / 3 - 1, xx = x + k9 % 3 - 1;
        float xv = (yy >= 0 && yy < N && xx >= 0 && xx < N) ? xb[(size_t)i * N * N + yy * N + xx] : 0.f;
        const float* __restrict__ e0 = Ec + (size_t)((oA * nci + i) * 9 + k9) * 28;
        const float* __restrict__ e1 = Ec + (size_t)((oB * nci + i) * 9 + k9) * 28;
        float kv0 = e0[25], kv1 = e1[25];
        #pragma unroll
        for (int uv = 0; uv < 25; ++uv) {
          kv0 = fmaf(e0[uv], P[uv], kv0);
          kv1 = fmaf(e1[uv], P[uv], kv1);
        }
        acc0 = fmaf(kv0, xv, acc0);
        acc1 = fmaf(kv1, xv, acc1);
      }
    }
    if (act) {
      float v0 = acc0 > 0.f ? acc0 : expm1f(acc0);
      float v1 = acc1 > 0.f ? acc1 : expm1f(acc1);
      xout[(((size_t)b * NCH + oA) * N + y) * N + x] = v0;
      xout[(((size_t)b * NCH + oB) * N + y) * N + x] = v1;
    }
    return;
  }

  // ---------------- corners: one block per scale; 4 corners x 8b x 8o = 256 thr ----
  {
    const float* __restrict__ E;
    int s = bid - e012e;
    if (s == 0)      { xin = xi0; xout = xo0; img = im0; E = Ee0; N = N0; nci = nci0; }
    else if (s == 1) { xin = xi1; xout = xo1; img = im1; E = Ee1; N = N1; nci = nci1; }
    else             { xin = xi2; xout = xo2; img = im2; E = Ee2; N = N2; nci = nci2; }

    int corner = threadIdx.x >> 6;  // 0..3
    int lane = threadIdx.x & 63;
    int y = (corner & 2) ? N - 1 : 0;
    int x = (corner & 1) ? N - 1 : 0;
    int cls = ((corner & 2) ? 6 : 0) + ((corner & 1) ? 2 : 0);
    int b = lane >> 3;
    int o = lane & 7;

    const float* __restrict__ Ec = E + (size_t)cls * 576 * 28;
    const float* imb = img + (size_t)b * N * N;
    float P[25];
    #pragma unroll
    for (int u = 0; u < 5; ++u)
      #pragma unroll
      for (int v = 0; v < 5; ++v) {
        int gy = y + u - 2, gx = x + v - 2;
        P[u * 5 + v] = (gy >= 0 && gy < N && gx >= 0 && gx < N) ? imb[gy * N + gx] : 0.f;
      }
    const float* xb = xin + (size_t)b * nci * N * N;
    float acc = 0.f;
    for (int i = 0; i < nci; ++i) {
      #pragma unroll 1
      for (int k9 = 0; k9 < 9; ++k9) {
        int yy = y + k9 / 3 - 1, xx = x + k9 % 3 - 1;
        float xv = (yy >= 0 && yy < N && xx >= 0 && xx < N) ? xb[(size_t)i * N * N + yy * N + xx] : 0.f;
        const float* e = Ec + (size_t)((o * nci + i) * 9 + k9) * 28;
        float kv = e[25];
        #pragma unroll
        for (int uv = 0; uv < 25; ++uv) kv = fmaf(e[uv], P[uv], kv);
        acc = fmaf(kv, xv, acc);
      }
    }
    float v0 = acc > 0.f ? acc : expm1f(acc);
    xout[(((size_t)b * NCH + o) * N + y) * N + x] = v0;
  }
}

__global__ __launch_bounds__(256) void final_merge(
    const float* __restrict__ x, const float* __restrict__ x1, const float* __restrict__ x2,
    const float* __restrict__ w5, const float* __restrict__ b5,
    const float* __restrict__ w6, const float* __restrict__ b6,
    float* __restrict__ out)
{
  int tid = blockIdx.x * 256 + threadIdx.x;
  if (tid >= 8 * 128 * 128) return;
  int xx = tid % 128, y = (tid / 128) % 128, b = tid / 16384;
  float v[NCH];
  #pragma unroll
  for (int i = 0; i < NCH; ++i) {
    v[i] = x[((size_t)(b * NCH + i) * 128 + y) * 128 + xx]
         + x1[((size_t)(b * NCH + i) * 64 + (y >> 1)) * 64 + (xx >> 1)]
         + x2[((size_t)(b * NCH + i) * 32 + (y >> 2)) * 32 + (xx >> 2)];
  }
  float o6 = b6[0];
  #pragma unroll
  for (int o = 0; o < NCH; ++o) {
    float h = b5[o];
    #pragma unroll
    for (int i = 0; i < NCH; ++i) h = fmaf(w5[o * NCH + i], v[i], h);
    h = h > 0.f ? h : expm1f(h);
    o6 = fmaf(w6[o], h, o6);
  }
  out[tid] = o6;
}

extern "C" void kernel_launch(void* const* d_in, const int* in_sizes, int n_in,
                              void* d_out, int out_size, void* d_ws, size_t ws_size,
                              hipStream_t stream) {
  const float* image = (const float*)d_in[0];
  const float* x_in  = (const float*)d_in[1];
  const float* iW1   = (const float*)d_in[2];
  const float* ib1   = (const float*)d_in[3];
  const float* iW2   = (const float*)d_in[4];
  const float* ib2   = (const float*)d_in[5];
  const float* bW1   = (const float*)d_in[6];
  const float* bb1   = (const float*)d_in[7];
  const float* bW2   = (const float*)d_in[8];
  const float* bb2   = (const float*)d_in[9];
  const float* w5    = (const float*)d_in[10];
  const float* b5    = (const float*)d_in[11];
  const float* w6    = (const float*)d_in[12];
  const float* b6    = (const float*)d_in[13];
  float* ws = (float*)d_ws;

  float* F    = ws + OFF_F;
  float* Bab  = ws + OFF_BAB;
  float* E    = ws + OFF_E;
  float* Epad = ws + OFF_EPAD;
  float* i1   = ws + OFF_I1;
  float* i2   = ws + OFF_I2;
  float* xA   = ws + OFF_XA;
  float* xB   = ws + OFF_XB;
  float* x1A  = ws + OFF_X1A;
  float* x1B  = ws + OFF_X1B;
  float* x2A  = ws + OFF_X2A;
  float* x2B  = ws + OFF_X2B;

  precomp_f_imgdown<<<2530, 256, 0, stream>>>(iW1, iW2, ib1, bW1, bW2, bb1, F, Bab, image, i1, i2);
  precomp_e<<<6582, 256, 0, stream>>>(F, Bab, ib2, bb2, E, Epad);

  // ---- init (blk 0, nc_in=1, scale0 only) ----
  // interior: 8b * 16 tiles(32x32) * 4og = 512; edges 4*8*2 = 64; corner 1 -> 577
  sm_step<<<577, 256, 0, stream>>>(
      x_in, xA, image, Epad, E, 128, 1,
      x_in, xA, image, Epad, E, 128, 1,
      x_in, xA, image, Epad, E, 128, 1,
      512, 512, 512, 576, 576, 576);
  x_down<<<1280, 256, 0, stream>>>(xA, x1A, x2A);

  float* xr = xA; float* xw = xB;
  float* x1r = x1A; float* x1w = x1B;
  float* x2r = x2A; float* x2w = x2B;
  for (int t = 0; t < 4; ++t) {
    const float* ei0 = Epad + (size_t)(1 + 3 * t) * EPBLK;
    const float* ei1 = Epad + (size_t)(2 + 3 * t) * EPBLK;
    const float* ei2 = Epad + (size_t)(3 + 3 * t) * EPBLK;
    const float* ee0 = E + (1 + 3 * t) * EBLKF;
    const float* ee1 = E + (2 + 3 * t) * EBLKF;
    const float* ee2 = E + (3 + 3 * t) * EBLKF;
    // interior: 512 + 128 + 32 = 672; edges: 64 + 32 + 32 = 128; corners: 3 -> 803
    sm_step<<<803, 256, 0, stream>>>(
        xr, xw, image, ei0, ee0, 128, 8,
        x1r, x1w, i1, ei1, ee1, 64, 8,
        x2r, x2w, i2, ei2, ee2, 32, 8,
        512, 640, 672, 736, 768, 800);
    float* tmp;
    tmp = xr; xr = xw; xw = tmp;
    tmp = x1r; x1r = x1w; x1w = tmp;
    tmp = x2r; x2r = x2w; x2w = tmp;
  }
  final_merge<<<512, 256, 0, stream>>>(xr, x1r, x2r, w5, b5, w6, b6, (float*)d_out);
}

// Round 8
// 597.479 us; speedup vs baseline: 1.2102x; 1.2102x over previous
//
#include <hip/hip_runtime.h>
#include <math.h>

#define NCH 8
#define HID 20

// ---- workspace layout (float offsets) ----
#define OFF_F    0u            // 13*576*81   = 606528
#define OFF_BAB  606528u       // 13*576*9    = 67392
#define OFF_E    673920u       // 13*9*576*28 = 1886976  (row: E[0..24], [25]=beta)
#define OFF_I1   2560896u      // 8*64*64
#define OFF_I2   2593664u      // 8*32*32
#define OFF_XA   2601856u      // 8*8*128*128
#define OFF_XB   3650432u
#define OFF_X1A  4699008u      // 8*8*64*64
#define OFF_X1B  4961152u
#define OFF_X2A  5223296u      // 8*8*32*32
#define OFF_X2B  5288832u
#define OFF_EPAD 5354368u      // 13 * 5184 * 32 = 2156544  (interior class, 128B rows)

#define EBLKF ((size_t)9 * 576 * 28)
#define EPBLK ((size_t)5184 * 32)

// K1: precomp_f (F/Bab) + img_down fused.
__global__ __launch_bounds__(256) void precomp_f_imgdown(
    const float* __restrict__ iW1, const float* __restrict__ iW2, const float* __restrict__ ib1,
    const float* __restrict__ bW1, const float* __restrict__ bW2, const float* __restrict__ bb1,
    float* __restrict__ F, float* __restrict__ Bab,
    const float* __restrict__ image, float* __restrict__ i1, float* __restrict__ i2)
{
  if (blockIdx.x >= 2370) {
    int tid = (blockIdx.x - 2370) * 256 + threadIdx.x;
    if (tid < 8 * 64 * 64) {
      int xx = tid % 64, y = (tid / 64) % 64, b = tid / 4096;
      const float* p = image + ((size_t)b * 128 + y * 2) * 128 + xx * 2;
      i1[tid] = 0.25f * (p[0] + p[1] + p[128] + p[129]);
    } else {
      int t = tid - 8 * 64 * 64;
      if (t >= 8 * 32 * 32) return;
      int xx = t % 32, y = (t / 32) % 32, b = t / 1024;
      const float* p = image + ((size_t)b * 128 + y * 4) * 128 + xx * 4;
      float s = 0.f;
      #pragma unroll
      for (int rr = 0; rr < 4; ++rr)
        #pragma unroll
        for (int cc = 0; cc < 4; ++cc) s += p[rr * 128 + cc];
      i2[t] = s * 0.0625f;
    }
    return;
  }
  int tid = blockIdx.x * 256 + threadIdx.x;
  if (tid >= 13 * 576 * 81) return;
  int ab9 = tid % 81;
  int rest = tid / 81;
  int p = rest % 576;
  int blk = rest / 576;
  if (blk == 0 && p >= 72) return;
  int ab = ab9 / 9, apbp = ab9 % 9;
  const float *W2, *W1, *b1;
  if (blk == 0) { W2 = iW2; W1 = iW1; b1 = ib1; }
  else {
    W2 = bW2 + (size_t)(blk - 1) * 576 * HID * 9;
    W1 = bW1 + (size_t)(blk - 1) * 64 * HID * 9;
    b1 = bb1 + (size_t)(blk - 1) * 64 * HID;
  }
  int g = p / 9;
  const float* w2p = W2 + (size_t)p * HID * 9 + ab;
  const float* w1p = W1 + (size_t)g * HID * 9 + apbp;
  float s = 0.f;
  #pragma unroll
  for (int cc = 0; cc < HID; ++cc) s = fmaf(w2p[cc * 9], w1p[cc * 9], s);
  F[(size_t)(blk * 576 + p) * 81 + ab9] = s;
  if (apbp == 0) {
    const float* b1p = b1 + g * HID;
    float sb = 0.f;
    #pragma unroll
    for (int cc = 0; cc < HID; ++cc) sb = fmaf(w2p[cc * 9], b1p[cc], sb);
    Bab[(size_t)(blk * 576 + p) * 9 + ab] = sb;
  }
}

// K2: E-class tables + padded interior copy (Epad rows = 32 floats, 128B aligned).
__global__ __launch_bounds__(256) void precomp_e(
    const float* __restrict__ F, const float* __restrict__ Bab,
    const float* __restrict__ ib2, const float* __restrict__ bb2,
    float* __restrict__ E, float* __restrict__ Epad)
{
  int tid = blockIdx.x * 256 + threadIdx.x;
  if (tid >= 13 * 9 * 576 * 25) return;
  int uv = tid % 25;
  int rest = tid / 25;
  int p = rest % 576;
  int rest2 = rest / 576;
  int cls = rest2 % 9;
  int blk = rest2 / 9;
  if (blk == 0 && p >= 72) return;
  int yc = cls / 3, xc = cls % 3;
  int alo = (yc == 0) ? 1 : 0, ahi = (yc == 2) ? 1 : 2;
  int blo = (xc == 0) ? 1 : 0, bhi = (xc == 2) ? 1 : 2;
  int u = uv / 5, v = uv % 5;
  const float* Fp = F + (size_t)(blk * 576 + p) * 81;
  float s = 0.f;
  for (int a = alo; a <= ahi; ++a) {
    int a2 = u - a;
    if (a2 < 0 || a2 > 2) continue;
    for (int bq = blo; bq <= bhi; ++bq) {
      int b2i = v - bq;
      if (b2i < 0 || b2i > 2) continue;
      s += Fp[(a * 3 + bq) * 9 + a2 * 3 + b2i];
    }
  }
  float* Ep = E + (size_t)((blk * 9 + cls) * 576 + p) * 28;
  Ep[uv] = s;
  float beta = 0.f;
  if (uv == 0) {
    beta = (blk == 0) ? ib2[p] : bb2[(size_t)(blk - 1) * 576 + p];
    const float* Bp = Bab + (size_t)(blk * 576 + p) * 9;
    for (int a = alo; a <= ahi; ++a)
      for (int bq = blo; bq <= bhi; ++bq)
        beta += Bp[a * 3 + bq];
    Ep[25] = beta;
  }
  if (cls == 4) {
    float* q = Epad + blk * EPBLK + (size_t)p * 32;
    q[uv] = s;
    if (uv == 0) q[25] = beta;
  }
}

__global__ __launch_bounds__(256) void x_down(
    const float* __restrict__ x, float* __restrict__ x1, float* __restrict__ x2)
{
  int tid = blockIdx.x * 256 + threadIdx.x;
  if (tid < 8 * NCH * 64 * 64) {
    int xx = tid % 64, y = (tid / 64) % 64, rest = tid / 4096;
    const float* p = x + ((size_t)rest * 128 + y * 2) * 128 + xx * 2;
    x1[tid] = 0.25f * (p[0] + p[1] + p[128] + p[129]);
  } else {
    int t = tid - 8 * NCH * 64 * 64;
    if (t >= 8 * NCH * 32 * 32) return;
    int xx = t % 32, y = (t / 32) % 32, rest = t / 1024;
    const float* p = x + ((size_t)rest * 128 + y * 4) * 128 + xx * 4;
    float s = 0.f;
    #pragma unroll
    for (int rr = 0; rr < 4; ++rr)
      #pragma unroll
      for (int cc = 0; cc < 4; ++cc) s += p[rr * 128 + cc];
    x2[t] = s * 0.0625f;
  }
}

#define TW 32
#define TH 32

// Unified per-step kernel. Interior: 32x32 tile, thread = 4-row strip, ONE o-chan.
// E rows (26 floats) software-prefetched one (i,k9) body ahead; patch direct from
// global (no is[] LDS stage) -> 36KB LDS -> 4 blocks/CU.
__global__ __launch_bounds__(256, 2) void sm_step(
    const float* __restrict__ xi0, float* __restrict__ xo0, const float* __restrict__ im0, const float* __restrict__ Ei0, const float* __restrict__ Ee0, int N0, int nci0,
    const float* __restrict__ xi1, float* __restrict__ xo1, const float* __restrict__ im1, const float* __restrict__ Ei1, const float* __restrict__ Ee1, int N1, int nci1,
    const float* __restrict__ xi2, float* __restrict__ xo2, const float* __restrict__ im2, const float* __restrict__ Ei2, const float* __restrict__ Ee2, int N2, int nci2,
    int i0, int i01, int i012, int e0e, int e01e, int e012e)
{
  __shared__ float xs[NCH][TH + 2][TW + 2];

  int bid = blockIdx.x;
  const float* __restrict__ xin;
  float* __restrict__ xout;
  const float* __restrict__ img;
  int N, nci;

  if (bid < i012) {
    // ---------------- interior ----------------
    const float* __restrict__ Ei;
    int lb, s;
    if (bid < i0)       { s = 0; lb = bid; }
    else if (bid < i01) { s = 1; lb = bid - i0; }
    else                { s = 2; lb = bid - i01; }
    if (s == 0)      { xin = xi0; xout = xo0; img = im0; Ei = Ei0; N = N0; nci = nci0; }
    else if (s == 1) { xin = xi1; xout = xo1; img = im1; Ei = Ei1; N = N1; nci = nci1; }
    else             { xin = xi2; xout = xo2; img = im2; Ei = Ei2; N = N2; nci = nci2; }

    int og = lb & 7;             // one output channel per block
    int rem = lb >> 3;
    int tilesx = N / TW;
    int tiles = tilesx * (N / TH);
    int b = rem / tiles;
    int trem = rem % tiles;
    int ty = trem / tilesx, tx = trem % tilesx;
    int X0 = tx * TW, Y0 = ty * TH;

    const float* xinb = xin + (size_t)b * nci * N * N;
    for (int idx = threadIdx.x; idx < nci * (TH + 2) * (TW + 2); idx += 256) {
      int cc = idx % (TW + 2);
      int rr = idx / (TW + 2);
      int r2 = rr % (TH + 2);
      int i = rr / (TH + 2);
      int gy = Y0 + r2 - 1, gx = X0 + cc - 1;
      float v = 0.f;
      if (gy >= 0 && gy < N && gx >= 0 && gx < N) v = xinb[(size_t)i * N * N + gy * N + gx];
      xs[i][r2][cc] = v;
    }

    int c = threadIdx.x & 31;
    int r = threadIdx.x >> 5;   // 0..7
    int R = r * 4;              // pixel rows R..R+3; patch rows R-2..R+5

    // 40-value img patch straight from global (one-time; L1-heavy)
    const float* imgb = img + (size_t)b * N * N;
    float pr[8][5];
    #pragma unroll
    for (int u = 0; u < 8; ++u)
      #pragma unroll
      for (int v = 0; v < 5; ++v) {
        int gy = Y0 + R + u - 2, gx = X0 + c + v - 2;
        pr[u][v] = (gy >= 0 && gy < N && gx >= 0 && gx < N) ? imgb[gy * N + gx] : 0.f;
      }
    asm volatile("" : "+v"(pr[0][0]), "+v"(pr[0][1]), "+v"(pr[0][2]), "+v"(pr[0][3]), "+v"(pr[0][4]),
                     "+v"(pr[1][0]), "+v"(pr[1][1]), "+v"(pr[1][2]), "+v"(pr[1][3]), "+v"(pr[1][4]),
                     "+v"(pr[2][0]), "+v"(pr[2][1]), "+v"(pr[2][2]), "+v"(pr[2][3]), "+v"(pr[2][4]),
                     "+v"(pr[3][0]), "+v"(pr[3][1]), "+v"(pr[3][2]), "+v"(pr[3][3]), "+v"(pr[3][4]));
    asm volatile("" : "+v"(pr[4][0]), "+v"(pr[4][1]), "+v"(pr[4][2]), "+v"(pr[4][3]), "+v"(pr[4][4]),
                     "+v"(pr[5][0]), "+v"(pr[5][1]), "+v"(pr[5][2]), "+v"(pr[5][3]), "+v"(pr[5][4]),
                     "+v"(pr[6][0]), "+v"(pr[6][1]), "+v"(pr[6][2]), "+v"(pr[6][3]), "+v"(pr[6][4]),
                     "+v"(pr[7][0]), "+v"(pr[7][1]), "+v"(pr[7][2]), "+v"(pr[7][3]), "+v"(pr[7][4]));

    __syncthreads();

    float acc[4];
    #pragma unroll
    for (int j = 0; j < 4; ++j) acc[j] = 0.f;

    const float* __restrict__ Ea = Ei + (size_t)(og * nci) * 9 * 32;
    const int NIK = nci * 9;

    float A[26], An[26];
    #pragma unroll
    for (int uv = 0; uv < 26; ++uv) A[uv] = Ea[uv];

    #pragma unroll 2
    for (int ik = 0; ik < NIK; ++ik) {
      // prefetch next body's E row while computing this one
      if (ik + 1 < NIK) {
        const float* __restrict__ en = Ea + (size_t)(ik + 1) * 32;
        #pragma unroll
        for (int uv = 0; uv < 26; ++uv) An[uv] = en[uv];
      }
      int i = ik / 9;
      int k9 = ik - i * 9;
      int dy = k9 / 3, dx = k9 - dy * 3;
      float xp[4];
      #pragma unroll
      for (int j = 0; j < 4; ++j) xp[j] = xs[i][R + j + dy][c + dx];
      float kv[4];
      #pragma unroll
      for (int j = 0; j < 4; ++j) kv[j] = A[25];
      #pragma unroll
      for (int u = 0; u < 5; ++u)
        #pragma unroll
        for (int v = 0; v < 5; ++v) {
          const int uv = u * 5 + v;
          const float c0 = A[uv];
          #pragma unroll
          for (int j = 0; j < 4; ++j) kv[j] = fmaf(c0, pr[u + j][v], kv[j]);
        }
      #pragma unroll
      for (int j = 0; j < 4; ++j) acc[j] = fmaf(kv[j], xp[j], acc[j]);
      #pragma unroll
      for (int uv = 0; uv < 26; ++uv) A[uv] = An[uv];
    }

    const int gx = X0 + c;
    float* yb = xout + ((size_t)b * NCH + og) * N * N;
    bool cok = (gx > 0) & (gx < N - 1);
    #pragma unroll
    for (int j = 0; j < 4; ++j) {
      int gy = Y0 + R + j;
      if (cok & (gy > 0) & (gy < N - 1)) {
        float v0 = acc[j]; v0 = v0 > 0.f ? v0 : expm1f(v0);
        yb[gy * N + gx] = v0;
      }
    }
    return;
  }

  if (bid < e012e) {
    // ---------------- edges (excl corners) ----------------
    const float* __restrict__ E;
    int eb = bid - i012;
    int lb, s;
    if (eb < e0e - i012)        { s = 0; lb = eb; }
    else if (eb < e01e - i012)  { s = 1; lb = eb - (e0e - i012); }
    else                        { s = 2; lb = eb - (e01e - i012); }
    if (s == 0)      { xin = xi0; xout = xo0; img = im0; E = Ee0; N = N0; nci = nci0; }
    else if (s == 1) { xin = xi1; xout = xo1; img = im1; E = Ee1; N = N1; nci = nci1; }
    else             { xin = xi2; xout = xo2; img = im2; E = Ee2; N = N2; nci = nci2; }

    int H = (N - 2 + 63) / 64;
    int half = lb % H;
    int b = (lb / H) % 8;
    int side = lb / (H * 8);

    int lane = threadIdx.x & 63;
    int orow = threadIdx.x >> 6;   // 0..3 (wave-uniform)
    int pos = 1 + half * 64 + lane;
    bool act = pos < N - 1;
    if (!act) pos = 1;

    int y, x, cls;
    if (side == 0)      { y = 0;     x = pos;  cls = 1; }
    else if (side == 1) { y = N - 1; x = pos;  cls = 7; }
    else if (side == 2) { x = 0;     y = pos;  cls = 3; }
    else                { x = N - 1; y = pos;  cls = 5; }

    const float* __restrict__ Ec = E + (size_t)cls * 576 * 28;
    const float* imb = img + (size_t)b * N * N;
    float P[25];
    #pragma unroll
    for (int u = 0; u < 5; ++u)
      #pragma unroll
      for (int v = 0; v < 5; ++v) {
        int gy = y + u - 2, gx = x + v - 2;
        P[u * 5 + v] = (gy >= 0 && gy < N && gx >= 0 && gx < N) ? imb[gy * N + gx] : 0.f;
      }

    const float* xb = xin + (size_t)b * nci * N * N;
    float acc0 = 0.f, acc1 = 0.f;
    const int oA = orow, oB = orow + 4;
    for (int i = 0; i < nci; ++i) {
      #pragma unroll 1
      for (int k9 = 0; k9 < 9; ++k9) {
        int yy = y + k9 / 3 - 1, xx = x + k9 % 3 - 1;
        float xv = (yy >= 0 && yy < N && xx >= 0 && xx < N) ? xb[(size_t)i * N * N + yy * N + xx] : 0.f;
        const float* __restrict__ e0 = Ec + (size_t)((oA * nci + i) * 9 + k9) * 28;
        const float* __restrict__ e1 = Ec + (size_t)((oB * nci + i) * 9 + k9) * 28;
        float kv0 = e0[25], kv1 = e1[25];
        #pragma unroll
        for (int uv = 0; uv < 25; ++uv) {
          kv0 = fmaf(e0[uv], P[uv], kv0);
          kv1 = fmaf(e1[uv], P[uv], kv1);
        }
        acc0 = fmaf(kv0, xv, acc0);
        acc1 = fmaf(kv1, xv, acc1);
      }
    }
    if (act) {
      float v0 = acc0 > 0.f ? acc0 : expm1f(acc0);
      float v1 = acc1 > 0.f ? acc1 : expm1f(acc1);
      xout[(((size_t)b * NCH + oA) * N + y) * N + x] = v0;
      xout[(((size_t)b * NCH + oB) * N + y) * N + x] = v1;
    }
    return;
  }

  // ---------------- corners ----------------
  {
    const float* __restrict__ E;
    int s = bid - e012e;
    if (s == 0)      { xin = xi0; xout = xo0; img = im0; E = Ee0; N = N0; nci = nci0; }
    else if (s == 1) { xin = xi1; xout = xo1; img = im1; E = Ee1; N = N1; nci = nci1; }
    else             { xin = xi2; xout = xo2; img = im2; E = Ee2; N = N2; nci = nci2; }

    int corner = threadIdx.x >> 6;  // 0..3
    int lane = threadIdx.x & 63;
    int y = (corner & 2) ? N - 1 : 0;
    int x = (corner & 1) ? N - 1 : 0;
    int cls = ((corner & 2) ? 6 : 0) + ((corner & 1) ? 2 : 0);
    int b = lane >> 3;
    int o = lane & 7;

    const float* __restrict__ Ec = E + (size_t)cls * 576 * 28;
    const float* imb = img + (size_t)b * N * N;
    float P[25];
    #pragma unroll
    for (int u = 0; u < 5; ++u)
      #pragma unroll
      for (int v = 0; v < 5; ++v) {
        int gy = y + u - 2, gx = x + v - 2;
        P[u * 5 + v] = (gy >= 0 && gy < N && gx >= 0 && gx < N) ? imb[gy * N + gx] : 0.f;
      }
    const float* xb = xin + (size_t)b * nci * N * N;
    float acc = 0.f;
    for (int i = 0; i < nci; ++i) {
      #pragma unroll 1
      for (int k9 = 0; k9 < 9; ++k9) {
        int yy = y + k9 / 3 - 1, xx = x + k9 % 3 - 1;
        float xv = (yy >= 0 && yy < N && xx >= 0 && xx < N) ? xb[(size_t)i * N * N + yy * N + xx] : 0.f;
        const float* e = Ec + (size_t)((o * nci + i) * 9 + k9) * 28;
        float kv = e[25];
        #pragma unroll
        for (int uv = 0; uv < 25; ++uv) kv = fmaf(e[uv], P[uv], kv);
        acc = fmaf(kv, xv, acc);
      }
    }
    float v0 = acc > 0.f ? acc : expm1f(acc);
    xout[(((size_t)b * NCH + o) * N + y) * N + x] = v0;
  }
}

__global__ __launch_bounds__(256) void final_merge(
    const float* __restrict__ x, const float* __restrict__ x1, const float* __restrict__ x2,
    const float* __restrict__ w5, const float* __restrict__ b5,
    const float* __restrict__ w6, const float* __restrict__ b6,
    float* __restrict__ out)
{
  int tid = blockIdx.x * 256 + threadIdx.x;
  if (tid >= 8 * 128 * 128) return;
  int xx = tid % 128, y = (tid / 128) % 128, b = tid / 16384;
  float v[NCH];
  #pragma unroll
  for (int i = 0; i < NCH; ++i) {
    v[i] = x[((size_t)(b * NCH + i) * 128 + y) * 128 + xx]
         + x1[((size_t)(b * NCH + i) * 64 + (y >> 1)) * 64 + (xx >> 1)]
         + x2[((size_t)(b * NCH + i) * 32 + (y >> 2)) * 32 + (xx >> 2)];
  }
  float o6 = b6[0];
  #pragma unroll
  for (int o = 0; o < NCH; ++o) {
    float h = b5[o];
    #pragma unroll
    for (int i = 0; i < NCH; ++i) h = fmaf(w5[o * NCH + i], v[i], h);
    h = h > 0.f ? h : expm1f(h);
    o6 = fmaf(w6[o], h, o6);
  }
  out[tid] = o6;
}

extern "C" void kernel_launch(void* const* d_in, const int* in_sizes, int n_in,
                              void* d_out, int out_size, void* d_ws, size_t ws_size,
                              hipStream_t stream) {
  const float* image = (const float*)d_in[0];
  const float* x_in  = (const float*)d_in[1];
  const float* iW1   = (const float*)d_in[2];
  const float* ib1   = (const float*)d_in[3];
  const float* iW2   = (const float*)d_in[4];
  const float* ib2   = (const float*)d_in[5];
  const float* bW1   = (const float*)d_in[6];
  const float* bb1   = (const float*)d_in[7];
  const float* bW2   = (const float*)d_in[8];
  const float* bb2   = (const float*)d_in[9];
  const float* w5    = (const float*)d_in[10];
  const float* b5    = (const float*)d_in[11];
  const float* w6    = (const float*)d_in[12];
  const float* b6    = (const float*)d_in[13];
  float* ws = (float*)d_ws;

  float* F    = ws + OFF_F;
  float* Bab  = ws + OFF_BAB;
  float* E    = ws + OFF_E;
  float* Epad = ws + OFF_EPAD;
  float* i1   = ws + OFF_I1;
  float* i2   = ws + OFF_I2;
  float* xA   = ws + OFF_XA;
  float* xB   = ws + OFF_XB;
  float* x1A  = ws + OFF_X1A;
  float* x1B  = ws + OFF_X1B;
  float* x2A  = ws + OFF_X2A;
  float* x2B  = ws + OFF_X2B;

  precomp_f_imgdown<<<2530, 256, 0, stream>>>(iW1, iW2, ib1, bW1, bW2, bb1, F, Bab, image, i1, i2);
  precomp_e<<<6582, 256, 0, stream>>>(F, Bab, ib2, bb2, E, Epad);

  // ---- init (blk 0, nc_in=1, scale0 only) ----
  // interior: 8b * 16 tiles * 8og = 1024; edges 4*8*2 = 64; corner 1 -> 1089
  sm_step<<<1089, 256, 0, stream>>>(
      x_in, xA, image, Epad, E, 128, 1,
      x_in, xA, image, Epad, E, 128, 1,
      x_in, xA, image, Epad, E, 128, 1,
      1024, 1024, 1024, 1088, 1088, 1088);
  x_down<<<1280, 256, 0, stream>>>(xA, x1A, x2A);

  float* xr = xA; float* xw = xB;
  float* x1r = x1A; float* x1w = x1B;
  float* x2r = x2A; float* x2w = x2B;
  for (int t = 0; t < 4; ++t) {
    const float* ei0 = Epad + (size_t)(1 + 3 * t) * EPBLK;
    const float* ei1 = Epad + (size_t)(2 + 3 * t) * EPBLK;
    const float* ei2 = Epad + (size_t)(3 + 3 * t) * EPBLK;
    const float* ee0 = E + (1 + 3 * t) * EBLKF;
    const float* ee1 = E + (2 + 3 * t) * EBLKF;
    const float* ee2 = E + (3 + 3 * t) * EBLKF;
    // interior: 1024 + 256 + 64 = 1344; edges: 64 + 32 + 32 = 128; corners: 3 -> 1475
    sm_step<<<1475, 256, 0, stream>>>(
        xr, xw, image, ei0, ee0, 128, 8,
        x1r, x1w, i1, ei1, ee1, 64, 8,
        x2r, x2w, i2, ei2, ee2, 32, 8,
        1024, 1280, 1344, 1408, 1440, 1472);
    float* tmp;
    tmp = xr; xr = xw; xw = tmp;
    tmp = x1r; x1r = x1w; x1w = tmp;
    tmp = x2r; x2r = x2w; x2w = tmp;
  }
  final_merge<<<512, 256, 0, stream>>>(xr, x1r, x2r, w5, b5, w6, b6, (float*)d_out);
}

// Round 9
// 559.279 us; speedup vs baseline: 1.2929x; 1.0683x over previous
//
#include <hip/hip_runtime.h>
#include <math.h>

#define NCH 8
#define HID 20

typedef __attribute__((ext_vector_type(8))) short short8v;
typedef __attribute__((ext_vector_type(4))) float f32x4;
typedef unsigned short ushort;
typedef unsigned int uint;

// ---- workspace layout (float offsets) ----
#define OFF_F    0u            // 13*576*81   = 606528
#define OFF_BAB  606528u       // 13*576*9    = 67392
#define OFF_E    673920u       // 13*9*576*28 = 1886976  (row: E[0..24], [25]=beta)
#define OFF_I1   2560896u      // 8*64*64
#define OFF_I2   2593664u      // 8*32*32
#define OFF_XA   2601856u      // 8*8*128*128
#define OFF_XB   3650432u
#define OFF_X1A  4699008u      // 8*8*64*64
#define OFF_X1B  4961152u
#define OFF_X2A  5223296u      // 8*8*32*32
#define OFF_X2B  5288832u
#define OFF_EBH  5354368u      // 13*576*32 ushort = 119808 floats (bf16-hi E, row=(ik*8+o), k25=beta)
#define OFF_EBL  5474176u      // 13*576*32 ushort (bf16-lo residual)

#define EBLKF ((size_t)9 * 576 * 28)

__device__ __forceinline__ ushort f2bf(float x) {
  uint u = __float_as_uint(x);
  uint r = (u + 0x7fffu + ((u >> 16) & 1u)) >> 16;
  return (ushort)r;
}
__device__ __forceinline__ float bf2f(ushort h) {
  return __uint_as_float(((uint)h) << 16);
}

// K1: precomp_f (F/Bab) + img_down fused.
__global__ __launch_bounds__(256) void precomp_f_imgdown(
    const float* __restrict__ iW1, const float* __restrict__ iW2, const float* __restrict__ ib1,
    const float* __restrict__ bW1, const float* __restrict__ bW2, const float* __restrict__ bb1,
    float* __restrict__ F, float* __restrict__ Bab,
    const float* __restrict__ image, float* __restrict__ i1, float* __restrict__ i2)
{
  if (blockIdx.x >= 2370) {
    int tid = (blockIdx.x - 2370) * 256 + threadIdx.x;
    if (tid < 8 * 64 * 64) {
      int xx = tid % 64, y = (tid / 64) % 64, b = tid / 4096;
      const float* p = image + ((size_t)b * 128 + y * 2) * 128 + xx * 2;
      i1[tid] = 0.25f * (p[0] + p[1] + p[128] + p[129]);
    } else {
      int t = tid - 8 * 64 * 64;
      if (t >= 8 * 32 * 32) return;
      int xx = t % 32, y = (t / 32) % 32, b = t / 1024;
      const float* p = image + ((size_t)b * 128 + y * 4) * 128 + xx * 4;
      float s = 0.f;
      #pragma unroll
      for (int rr = 0; rr < 4; ++rr)
        #pragma unroll
        for (int cc = 0; cc < 4; ++cc) s += p[rr * 128 + cc];
      i2[t] = s * 0.0625f;
    }
    return;
  }
  int tid = blockIdx.x * 256 + threadIdx.x;
  if (tid >= 13 * 576 * 81) return;
  int ab9 = tid % 81;
  int rest = tid / 81;
  int p = rest % 576;
  int blk = rest / 576;
  if (blk == 0 && p >= 72) return;
  int ab = ab9 / 9, apbp = ab9 % 9;
  const float *W2, *W1, *b1;
  if (blk == 0) { W2 = iW2; W1 = iW1; b1 = ib1; }
  else {
    W2 = bW2 + (size_t)(blk - 1) * 576 * HID * 9;
    W1 = bW1 + (size_t)(blk - 1) * 64 * HID * 9;
    b1 = bb1 + (size_t)(blk - 1) * 64 * HID;
  }
  int g = p / 9;
  const float* w2p = W2 + (size_t)p * HID * 9 + ab;
  const float* w1p = W1 + (size_t)g * HID * 9 + apbp;
  float s = 0.f;
  #pragma unroll
  for (int cc = 0; cc < HID; ++cc) s = fmaf(w2p[cc * 9], w1p[cc * 9], s);
  F[(size_t)(blk * 576 + p) * 81 + ab9] = s;
  if (apbp == 0) {
    const float* b1p = b1 + g * HID;
    float sb = 0.f;
    #pragma unroll
    for (int cc = 0; cc < HID; ++cc) sb = fmaf(w2p[cc * 9], b1p[cc], sb);
    Bab[(size_t)(blk * 576 + p) * 9 + ab] = sb;
  }
}

// K2: E-class tables (fp32, for edge/corner paths).
__global__ __launch_bounds__(256) void precomp_e(
    const float* __restrict__ F, const float* __restrict__ Bab,
    const float* __restrict__ ib2, const float* __restrict__ bb2,
    float* __restrict__ E)
{
  int tid = blockIdx.x * 256 + threadIdx.x;
  if (tid >= 13 * 9 * 576 * 25) return;
  int uv = tid % 25;
  int rest = tid / 25;
  int p = rest % 576;
  int rest2 = rest / 576;
  int cls = rest2 % 9;
  int blk = rest2 / 9;
  if (blk == 0 && p >= 72) return;
  int yc = cls / 3, xc = cls % 3;
  int alo = (yc == 0) ? 1 : 0, ahi = (yc == 2) ? 1 : 2;
  int blo = (xc == 0) ? 1 : 0, bhi = (xc == 2) ? 1 : 2;
  int u = uv / 5, v = uv % 5;
  const float* Fp = F + (size_t)(blk * 576 + p) * 81;
  float s = 0.f;
  for (int a = alo; a <= ahi; ++a) {
    int a2 = u - a;
    if (a2 < 0 || a2 > 2) continue;
    for (int bq = blo; bq <= bhi; ++bq) {
      int b2i = v - bq;
      if (b2i < 0 || b2i > 2) continue;
      s += Fp[(a * 3 + bq) * 9 + a2 * 3 + b2i];
    }
  }
  float* Ep = E + (size_t)((blk * 9 + cls) * 576 + p) * 28;
  Ep[uv] = s;
  if (uv == 0) {
    float beta = (blk == 0) ? ib2[p] : bb2[(size_t)(blk - 1) * 576 + p];
    const float* Bp = Bab + (size_t)(blk * 576 + p) * 9;
    for (int a = alo; a <= ahi; ++a)
      for (int bq = blo; bq <= bhi; ++bq)
        beta += Bp[a * 3 + bq];
    Ep[25] = beta;
  }
}

// K3: pack interior-class E into bf16 hi/lo tables, row = ik*8+o, k=0..24 coeffs,
// k=25 beta, k>=26 zero. blk0 (nci=1): 72 real rows, rest zero.
__global__ __launch_bounds__(256) void epack(
    const float* __restrict__ E, ushort* __restrict__ Ebh, ushort* __restrict__ Ebl)
{
  int tid = blockIdx.x * 256 + threadIdx.x;
  if (tid >= 13 * 576 * 32) return;
  int k = tid & 31;
  int row = (tid >> 5) % 576;
  int blk = tid / (576 * 32);
  ushort hi = 0, lo = 0;
  int nci = (blk == 0) ? 1 : 8;
  int rows_real = nci * 72;  // nci*9*8
  if (row < rows_real && k < 26) {
    int ik = row >> 3, o = row & 7;
    int i = ik / 9, k9 = ik % 9;
    int p = (o * nci + i) * 9 + k9;
    const float* src = E + ((size_t)(blk * 9 + 4) * 576 + p) * 28;
    float val = (k < 25) ? src[k] : src[25];
    hi = f2bf(val);
    lo = f2bf(val - bf2f(hi));
  }
  Ebh[tid] = hi;
  Ebl[tid] = lo;
}

__global__ __launch_bounds__(256) void x_down(
    const float* __restrict__ x, float* __restrict__ x1, float* __restrict__ x2)
{
  int tid = blockIdx.x * 256 + threadIdx.x;
  if (tid < 8 * NCH * 64 * 64) {
    int xx = tid % 64, y = (tid / 64) % 64, rest = tid / 4096;
    const float* p = x + ((size_t)rest * 128 + y * 2) * 128 + xx * 2;
    x1[tid] = 0.25f * (p[0] + p[1] + p[128] + p[129]);
  } else {
    int t = tid - 8 * NCH * 64 * 64;
    if (t >= 8 * NCH * 32 * 32) return;
    int xx = t % 32, y = (t / 32) % 32, rest = t / 1024;
    const float* p = x + ((size_t)rest * 128 + y * 4) * 128 + xx * 4;
    float s = 0.f;
    #pragma unroll
    for (int rr = 0; rr < 4; ++rr)
      #pragma unroll
      for (int cc = 0; cc < 4; ++cc) s += p[rr * 128 + cc];
    x2[t] = s * 0.0625f;
  }
}

// Unified per-step kernel. Interior = MFMA path: 16x16 px tile, 4 waves x 4 rows.
// GEMM: D[row=ik*8+o, px] = E[row, uv] . P[uv, px] via bf16 hi/lo split (3 MFMAs),
// beta folded at k=25 (P[25]=1). Then out[o,px] = sum_ik D*xp (VALU+shfl).
__global__ __launch_bounds__(256, 2) void sm_step(
    const float* __restrict__ xi0, float* __restrict__ xo0, const float* __restrict__ im0, const ushort* __restrict__ Eh0, const ushort* __restrict__ El0, const float* __restrict__ Ee0, int N0, int nci0,
    const float* __restrict__ xi1, float* __restrict__ xo1, const float* __restrict__ im1, const ushort* __restrict__ Eh1, const ushort* __restrict__ El1, const float* __restrict__ Ee1, int N1, int nci1,
    const float* __restrict__ xi2, float* __restrict__ xo2, const float* __restrict__ im2, const ushort* __restrict__ Eh2, const ushort* __restrict__ El2, const float* __restrict__ Ee2, int N2, int nci2,
    int i0, int i01, int i012, int e0e, int e01e, int e012e)
{
  __shared__ float xsl[NCH][18][18];   // x tile 16x16 + halo 1
  __shared__ float isl[20][20];        // img tile + halo 2

  int bid = blockIdx.x;
  int tid = threadIdx.x;
  const float* __restrict__ xin;
  float* __restrict__ xout;
  const float* __restrict__ img;
  int N, nci;

  if (bid < i012) {
    // ---------------- interior (MFMA) ----------------
    const ushort* __restrict__ EH;
    const ushort* __restrict__ EL;
    int lb, s;
    if (bid < i0)       { s = 0; lb = bid; }
    else if (bid < i01) { s = 1; lb = bid - i0; }
    else                { s = 2; lb = bid - i01; }
    if (s == 0)      { xin = xi0; xout = xo0; img = im0; EH = Eh0; EL = El0; N = N0; nci = nci0; }
    else if (s == 1) { xin = xi1; xout = xo1; img = im1; EH = Eh1; EL = El1; N = N1; nci = nci1; }
    else             { xin = xi2; xout = xo2; img = im2; EH = Eh2; EL = El2; N = N2; nci = nci2; }

    int tilesx = N >> 4;
    int tiles = tilesx * tilesx;
    int b = lb / tiles;
    int trem = lb % tiles;
    int ty = trem / tilesx, tx = trem % tilesx;
    int X0 = tx * 16, Y0 = ty * 16;

    // stage img tile (+2 halo) and x tile (+1 halo)
    const float* imgb = img + (size_t)b * N * N;
    for (int idx = tid; idx < 400; idx += 256) {
      int r = idx / 20, c = idx % 20;
      int gy = Y0 - 2 + r, gx = X0 - 2 + c;
      float v = 0.f;
      if (gy >= 0 && gy < N && gx >= 0 && gx < N) v = imgb[gy * N + gx];
      isl[r][c] = v;
    }
    const float* xinb = xin + (size_t)b * nci * N * N;
    for (int idx = tid; idx < nci * 324; idx += 256) {
      int i = idx / 324;
      int rem = idx - i * 324;
      int r = rem / 18, c = rem % 18;
      int gy = Y0 - 1 + r, gx = X0 - 1 + c;
      float v = 0.f;
      if (gy >= 0 && gy < N && gx >= 0 && gx < N) v = xinb[(size_t)i * N * N + gy * N + gx];
      xsl[i][r][c] = v;
    }
    __syncthreads();

    int l = tid & 63;
    int wid = tid >> 6;
    int c15 = l & 15;
    int kb = (l >> 4) * 8;
    int hi5 = l >> 5;
    const int T = (nci == 1) ? 5 : 36;       // M-tiles (rows padded to 80 for nci=1)
    const int nikr = nci * 9;

    #pragma unroll 1
    for (int g = 0; g < 4; ++g) {
      int pyl = wid * 4 + g;
      int py = Y0 + pyl;

      // build B fragments (patch, bf16 hi/lo); k=25 -> 1.0 (beta slot), k>25 -> 0
      short8v Ph, Pl;
      #pragma unroll
      for (int j = 0; j < 8; ++j) {
        int k = kb + j;
        int u = (k * 13) >> 6;
        int uc = u > 4 ? 4 : u;
        int v = k - 5 * uc;
        int vc = v > 4 ? 4 : (v < 0 ? 0 : v);
        float pv = isl[pyl + uc][c15 + vc];
        pv = (k < 25) ? pv : ((k == 25) ? 1.f : 0.f);
        ushort h = f2bf(pv);
        ushort lo = f2bf(pv - bf2f(h));
        Ph[j] = (short)h;
        Pl[j] = (short)lo;
      }

      f32x4 aco = {0.f, 0.f, 0.f, 0.f};
      #pragma unroll 2
      for (int mt = 0; mt < T; ++mt) {
        int row = mt * 16 + c15;
        short8v Ah = *(const short8v*)(EH + (size_t)row * 32 + kb);
        short8v Al = *(const short8v*)(EL + (size_t)row * 32 + kb);
        f32x4 d = {0.f, 0.f, 0.f, 0.f};
        d = __builtin_amdgcn_mfma_f32_16x16x32_bf16(Al, Ph, d, 0, 0, 0);
        d = __builtin_amdgcn_mfma_f32_16x16x32_bf16(Ah, Pl, d, 0, 0, 0);
        d = __builtin_amdgcn_mfma_f32_16x16x32_bf16(Ah, Ph, d, 0, 0, 0);
        int ik = 2 * mt + hi5;
        float xp = 0.f;
        if (ik < nikr) {
          int i = (ik * 57) >> 9;          // /9 for 0..71
          int k9 = ik - 9 * i;
          int dy = (k9 * 11) >> 5;         // /3 for 0..8
          int dx = k9 - 3 * dy;
          xp = xsl[i][pyl + dy][c15 + dx];
        }
        #pragma unroll
        for (int j = 0; j < 4; ++j) aco[j] = fmaf(d[j], xp, aco[j]);
      }

      // combine ik parities (lane ^ 32 has same o-quad & pixel)
      #pragma unroll
      for (int j = 0; j < 4; ++j) aco[j] += __shfl_xor(aco[j], 32, 64);

      if (l < 32) {
        int ob = ((l >> 4) & 1) * 4;
        int px = X0 + c15;
        if (px >= 1 && px <= N - 2 && py >= 1 && py <= N - 2) {
          float* yb = xout + (size_t)b * NCH * N * N;
          #pragma unroll
          for (int j = 0; j < 4; ++j) {
            float v = aco[j];
            v = v > 0.f ? v : expm1f(v);
            yb[(size_t)(ob + j) * N * N + py * N + px] = v;
          }
        }
      }
    }
    return;
  }

  if (bid < e012e) {
    // ---------------- edges (excl corners), VALU path ----------------
    const float* __restrict__ E;
    int eb = bid - i012;
    int lb, s;
    if (eb < e0e - i012)        { s = 0; lb = eb; }
    else if (eb < e01e - i012)  { s = 1; lb = eb - (e0e - i012); }
    else                        { s = 2; lb = eb - (e01e - i012); }
    if (s == 0)      { xin = xi0; xout = xo0; img = im0; E = Ee0; N = N0; nci = nci0; }
    else if (s == 1) { xin = xi1; xout = xo1; img = im1; E = Ee1; N = N1; nci = nci1; }
    else             { xin = xi2; xout = xo2; img = im2; E = Ee2; N = N2; nci = nci2; }

    int H = (N - 2 + 63) / 64;
    int half = lb % H;
    int b = (lb / H) % 8;
    int side = lb / (H * 8);

    int lane = tid & 63;
    int orow = tid >> 6;   // 0..3 (wave-uniform)
    int pos = 1 + half * 64 + lane;
    bool act = pos < N - 1;
    if (!act) pos = 1;

    int y, x, cls;
    if (side == 0)      { y = 0;     x = pos;  cls = 1; }
    else if (side == 1) { y = N - 1; x = pos;  cls = 7; }
    else if (side == 2) { x = 0;     y = pos;  cls = 3; }
    else                { x = N - 1; y = pos;  cls = 5; }

    const float* __restrict__ Ec = E + (size_t)cls * 576 * 28;
    const float* imb = img + (size_t)b * N * N;
    float P[25];
    #pragma unroll
    for (int u = 0; u < 5; ++u)
      #pragma unroll
      for (int v = 0; v < 5; ++v) {
        int gy = y + u - 2, gx = x + v - 2;
        P[u * 5 + v] = (gy >= 0 && gy < N && gx >= 0 && gx < N) ? imb[gy * N + gx] : 0.f;
      }

    const float* xb = xin + (size_t)b * nci * N * N;
    float acc0 = 0.f, acc1 = 0.f;
    const int oA = orow, oB = orow + 4;
    for (int i = 0; i < nci; ++i) {
      #pragma unroll 1
      for (int k9 = 0; k9 < 9; ++k9) {
        int yy = y + k9 / 3 - 1, xx = x + k9 % 3 - 1;
        float xv = (yy >= 0 && yy < N && xx >= 0 && xx < N) ? xb[(size_t)i * N * N + yy * N + xx] : 0.f;
        const float* __restrict__ e0 = Ec + (size_t)((oA * nci + i) * 9 + k9) * 28;
        const float* __restrict__ e1 = Ec + (size_t)((oB * nci + i) * 9 + k9) * 28;
        float kv0 = e0[25], kv1 = e1[25];
        #pragma unroll
        for (int uv = 0; uv < 25; ++uv) {
          kv0 = fmaf(e0[uv], P[uv], kv0);
          kv1 = fmaf(e1[uv], P[uv], kv1);
        }
        acc0 = fmaf(kv0, xv, acc0);
        acc1 = fmaf(kv1, xv, acc1);
      }
    }
    if (act) {
      float v0 = acc0 > 0.f ? acc0 : expm1f(acc0);
      float v1 = acc1 > 0.f ? acc1 : expm1f(acc1);
      xout[(((size_t)b * NCH + oA) * N + y) * N + x] = v0;
      xout[(((size_t)b * NCH + oB) * N + y) * N + x] = v1;
    }
    return;
  }

  // ---------------- corners ----------------
  {
    const float* __restrict__ E;
    int s = bid - e012e;
    if (s == 0)      { xin = xi0; xout = xo0; img = im0; E = Ee0; N = N0; nci = nci0; }
    else if (s == 1) { xin = xi1; xout = xo1; img = im1; E = Ee1; N = N1; nci = nci1; }
    else             { xin = xi2; xout = xo2; img = im2; E = Ee2; N = N2; nci = nci2; }

    int corner = tid >> 6;  // 0..3
    int lane = tid & 63;
    int y = (corner & 2) ? N - 1 : 0;
    int x = (corner & 1) ? N - 1 : 0;
    int cls = ((corner & 2) ? 6 : 0) + ((corner & 1) ? 2 : 0);
    int b = lane >> 3;
    int o = lane & 7;

    const float* __restrict__ Ec = E + (size_t)cls * 576 * 28;
    const float* imb = img + (size_t)b * N * N;
    float P[25];
    #pragma unroll
    for (int u = 0; u < 5; ++u)
      #pragma unroll
      for (int v = 0; v < 5; ++v) {
        int gy = y + u - 2, gx = x + v - 2;
        P[u * 5 + v] = (gy >= 0 && gy < N && gx >= 0 && gx < N) ? imb[gy * N + gx] : 0.f;
      }
    const float* xb = xin + (size_t)b * nci * N * N;
    float acc = 0.f;
    for (int i = 0; i < nci; ++i) {
      #pragma unroll 1
      for (int k9 = 0; k9 < 9; ++k9) {
        int yy = y + k9 / 3 - 1, xx = x + k9 % 3 - 1;
        float xv = (yy >= 0 && yy < N && xx >= 0 && xx < N) ? xb[(size_t)i * N * N + yy * N + xx] : 0.f;
        const float* e = Ec + (size_t)((o * nci + i) * 9 + k9) * 28;
        float kv = e[25];
        #pragma unroll
        for (int uv = 0; uv < 25; ++uv) kv = fmaf(e[uv], P[uv], kv);
        acc = fmaf(kv, xv, acc);
      }
    }
    float v0 = acc > 0.f ? acc : expm1f(acc);
    xout[(((size_t)b * NCH + o) * N + y) * N + x] = v0;
  }
}

__global__ __launch_bounds__(256) void final_merge(
    const float* __restrict__ x, const float* __restrict__ x1, const float* __restrict__ x2,
    const float* __restrict__ w5, const float* __restrict__ b5,
    const float* __restrict__ w6, const float* __restrict__ b6,
    float* __restrict__ out)
{
  int tid = blockIdx.x * 256 + threadIdx.x;
  if (tid >= 8 * 128 * 128) return;
  int xx = tid % 128, y = (tid / 128) % 128, b = tid / 16384;
  float v[NCH];
  #pragma unroll
  for (int i = 0; i < NCH; ++i) {
    v[i] = x[((size_t)(b * NCH + i) * 128 + y) * 128 + xx]
         + x1[((size_t)(b * NCH + i) * 64 + (y >> 1)) * 64 + (xx >> 1)]
         + x2[((size_t)(b * NCH + i) * 32 + (y >> 2)) * 32 + (xx >> 2)];
  }
  float o6 = b6[0];
  #pragma unroll
  for (int o = 0; o < NCH; ++o) {
    float h = b5[o];
    #pragma unroll
    for (int i = 0; i < NCH; ++i) h = fmaf(w5[o * NCH + i], v[i], h);
    h = h > 0.f ? h : expm1f(h);
    o6 = fmaf(w6[o], h, o6);
  }
  out[tid] = o6;
}

extern "C" void kernel_launch(void* const* d_in, const int* in_sizes, int n_in,
                              void* d_out, int out_size, void* d_ws, size_t ws_size,
                              hipStream_t stream) {
  const float* image = (const float*)d_in[0];
  const float* x_in  = (const float*)d_in[1];
  const float* iW1   = (const float*)d_in[2];
  const float* ib1   = (const float*)d_in[3];
  const float* iW2   = (const float*)d_in[4];
  const float* ib2   = (const float*)d_in[5];
  const float* bW1   = (const float*)d_in[6];
  const float* bb1   = (const float*)d_in[7];
  const float* bW2   = (const float*)d_in[8];
  const float* bb2   = (const float*)d_in[9];
  const float* w5    = (const float*)d_in[10];
  const float* b5    = (const float*)d_in[11];
  const float* w6    = (const float*)d_in[12];
  const float* b6    = (const float*)d_in[13];
  float* ws = (float*)d_ws;

  float* F    = ws + OFF_F;
  float* Bab  = ws + OFF_BAB;
  float* E    = ws + OFF_E;
  float* i1   = ws + OFF_I1;
  float* i2   = ws + OFF_I2;
  float* xA   = ws + OFF_XA;
  float* xB   = ws + OFF_XB;
  float* x1A  = ws + OFF_X1A;
  float* x1B  = ws + OFF_X1B;
  float* x2A  = ws + OFF_X2A;
  float* x2B  = ws + OFF_X2B;
  ushort* Ebh = (ushort*)(ws + OFF_EBH);
  ushort* Ebl = (ushort*)(ws + OFF_EBL);

  precomp_f_imgdown<<<2530, 256, 0, stream>>>(iW1, iW2, ib1, bW1, bW2, bb1, F, Bab, image, i1, i2);
  precomp_e<<<6582, 256, 0, stream>>>(F, Bab, ib2, bb2, E);
  epack<<<936, 256, 0, stream>>>(E, Ebh, Ebl);

  const size_t EPB = (size_t)576 * 32;

  // ---- init (blk 0, nc_in=1, scale0 only) ----
  // interior: 8b * 64 tiles(16x16) = 512; edges 4*8*2 = 64; corner 1 -> 577
  sm_step<<<577, 256, 0, stream>>>(
      x_in, xA, image, Ebh, Ebl, E, 128, 1,
      x_in, xA, image, Ebh, Ebl, E, 128, 1,
      x_in, xA, image, Ebh, Ebl, E, 128, 1,
      512, 512, 512, 576, 576, 576);
  x_down<<<1280, 256, 0, stream>>>(xA, x1A, x2A);

  float* xr = xA; float* xw = xB;
  float* x1r = x1A; float* x1w = x1B;
  float* x2r = x2A; float* x2w = x2B;
  for (int t = 0; t < 4; ++t) {
    int b0 = 1 + 3 * t, b1 = 2 + 3 * t, b2 = 3 + 3 * t;
    // interior: 512 + 128 + 32 = 672; edges: 64 + 32 + 32 = 128; corners: 3 -> 803
    sm_step<<<803, 256, 0, stream>>>(
        xr, xw, image, Ebh + b0 * EPB, Ebl + b0 * EPB, E + b0 * EBLKF, 128, 8,
        x1r, x1w, i1,  Ebh + b1 * EPB, Ebl + b1 * EPB, E + b1 * EBLKF, 64, 8,
        x2r, x2w, i2,  Ebh + b2 * EPB, Ebl + b2 * EPB, E + b2 * EBLKF, 32, 8,
        512, 640, 672, 736, 768, 800);
    float* tmp;
    tmp = xr; xr = xw; xw = tmp;
    tmp = x1r; x1r = x1w; x1w = tmp;
    tmp = x2r; x2r = x2w; x2w = tmp;
  }
  final_merge<<<512, 256, 0, stream>>>(xr, x1r, x2r, w5, b5, w6, b6, (float*)d_out);
}